// Round 10
// baseline (827.031 us; speedup 1.0000x reference)
//
#include <hip/hip_runtime.h>
#include <hip/hip_bf16.h>

typedef short bf16x8 __attribute__((ext_vector_type(8)));
typedef float f32x4 __attribute__((ext_vector_type(4)));
typedef unsigned short ushort8v __attribute__((ext_vector_type(8)));

#define SBAR() asm volatile("s_barrier" ::: "memory")

__device__ __forceinline__ unsigned short f2bf(float f) {
  unsigned u = __builtin_bit_cast(unsigned, f);
  u += 0x7fffu + ((u >> 16) & 1u);   // round-to-nearest-even
  return (unsigned short)(u >> 16);
}

__device__ __forceinline__ void gload_lds16(const unsigned short* g, unsigned short* l) {
  __builtin_amdgcn_global_load_lds((const __attribute__((address_space(1))) void*)g,
                                   (__attribute__((address_space(3))) void*)l, 16, 0, 0);
}

// ---------------- fused prep: xb = bf16(x); wb = bf16(W + scale*B@A) ----------------
__global__ __launch_bounds__(256) void prep_kernel(const float* __restrict__ x,
                                                   const float* __restrict__ W,
                                                   const float* __restrict__ A,
                                                   const float* __restrict__ Bm,
                                                   unsigned short* __restrict__ xb,
                                                   unsigned short* __restrict__ wb,
                                                   float scale, int K, int R, int n8, int t8) {
  int i = blockIdx.x * 256 + threadIdx.x;
  if (i < n8) {
    const float4* p = (const float4*)x + (size_t)i * 2;
    float4 a = p[0], b = p[1];
    ushort8v v;
    v[0] = f2bf(a.x); v[1] = f2bf(a.y); v[2] = f2bf(a.z); v[3] = f2bf(a.w);
    v[4] = f2bf(b.x); v[5] = f2bf(b.y); v[6] = f2bf(b.z); v[7] = f2bf(b.w);
    *((ushort8v*)xb + i) = v;
    return;
  }
  int idx = i - n8;
  if (idx >= t8) return;
  int perRow = K >> 3;
  int n = idx / perRow;
  int d0 = (idx - n * perRow) << 3;
  const float4* wp = (const float4*)(W + (size_t)n * K + d0);
  float4 w0 = wp[0], w1 = wp[1];
  float acc[8] = {w0.x, w0.y, w0.z, w0.w, w1.x, w1.y, w1.z, w1.w};
#pragma unroll 4
  for (int r = 0; r < R; ++r) {
    float c = Bm[(size_t)n * R + r] * scale;
    const float4* ap = (const float4*)(A + (size_t)r * K + d0);
    float4 a0 = ap[0], a1 = ap[1];
    acc[0] += c * a0.x; acc[1] += c * a0.y; acc[2] += c * a0.z; acc[3] += c * a0.w;
    acc[4] += c * a1.x; acc[5] += c * a1.y; acc[6] += c * a1.z; acc[7] += c * a1.w;
  }
  ushort8v v;
#pragma unroll
  for (int j = 0; j < 8; ++j) v[j] = f2bf(acc[j]);
  *((ushort8v*)wb + idx) = v;
}

// ------------- 256x256 bf16 GEMM: 1-phase-lead balanced 4-phase schedule -------------
// BK=64, 8 waves (2Mx4N, wave 128x64). LDS: A triple-buffered (3x32KB @0/32768/65536),
// B double-buffered (2x32KB @98304/131072) = 160KB. Each phase issues exactly 6
// ds_reads feeding LATER phases (never its own MFMA): M0:{bB4,aB2} M1:{aB6}
// M2:{aA[0..5] of c+1} M3:{aA[6..7],bA4 of c+1}. Counted lgkm (6/8/6/-) never
// stalls in steady state -> LDS pipe drains under MFMA clusters. Stage 2/phase
// (A(c+2)@M0/M1, B(c+2)@M2/M3); counted vmcnt(8)@endM1 certifies A(c+1),
// vmcnt(6)@endM2 certifies B(c+1) (loads aged 3-4 phases). In-place frag refill
// is hazard-free: each array refills exactly 2 phases after its last consumer.
__global__ __launch_bounds__(512, 2) void gemm256_bt_bias(const unsigned short* __restrict__ Xb,
                                                          const unsigned short* __restrict__ Wb,
                                                          const float* __restrict__ bias,
                                                          float* __restrict__ C,
                                                          int M, int N, int K) {
  __shared__ __align__(16) char lds[163840];
  const int t = threadIdx.x;
  const int wave = t >> 6, lane = t & 63;
  const int fr = lane & 15, kc = lane >> 4;
  const int wr = wave >> 2, wc = wave & 3;

  const int NTn = N >> 8;
  const int nwg = gridDim.x;
  int bid = blockIdx.x;
  if ((nwg & 7) == 0) bid = (bid & 7) * (nwg >> 3) + (bid >> 3);  // XCD swizzle
  const int tm = bid / NTn, tn = bid % NTn;
  const int m0 = tm << 8, n0 = tn << 8;

  // staging source (pre-swizzled global chunk: LDS chunk q holds G chunk q^(row&7))
  const int grow = t >> 3;
  const int gch8 = ((t & 7) ^ ((t >> 3) & 7)) << 3;
  const size_t K64 = (size_t)64 * K;
  const unsigned short* pa = Xb + (size_t)(m0 + grow) * K + gch8;
  const unsigned short* pb = Wb + (size_t)(n0 + grow) * K + gch8;
  const int sdst = t * 16;

  // per-lane read offsets (proven conflict-free swizzle)
  const int sw  = (lane & 7) << 4;
  const int cb0 = (kc << 4) ^ sw;
  const int cb1 = cb0 ^ 64;
  const int arA0 = (wr * 128 + fr) * 128 + cb0;
  const int arA1 = (wr * 128 + fr) * 128 + cb1;
  const int arB0 = (wc * 64 + fr) * 128 + cb0;
  const int arB1 = (wc * 64 + fr) * 128 + cb1;

#define AB0 0
#define AB1 32768
#define AB2 65536
#define BB0 98304
#define BB1 131072

  f32x4 acc[8][4];
#pragma unroll
  for (int m = 0; m < 8; ++m)
#pragma unroll
    for (int n = 0; n < 4; ++n) acc[m][n] = (f32x4){0.f, 0.f, 0.f, 0.f};

  bf16x8 aA[8], aB[8], bA[4], bB[4];
  const int NT = K >> 6;   // launcher guarantees NT % 6 == 4, NT >= 10

#define RD16(BI, LR) (*(const bf16x8*)((const char*)lds + (size_t)(BI) + (LR)))
#define STGA(AS, s) gload_lds16(pa + (size_t)(s) * K64, \
    (unsigned short*)((char*)lds + (AS) + (s) * 8192 + sdst))
#define STGB(BS, s) gload_lds16(pb + (size_t)(s) * K64, \
    (unsigned short*)((char*)lds + (BS) + (s) * 8192 + sdst))

#define MMQ(MO, NO, AF, BF) do { \
    _Pragma("unroll") for (int ks = 0; ks < 2; ++ks) \
    _Pragma("unroll") for (int m = 0; m < 4; ++m) \
    _Pragma("unroll") for (int n = 0; n < 2; ++n) \
      acc[(MO)+m][(NO)+n] = __builtin_amdgcn_mfma_f32_16x16x32_bf16( \
          AF[m*2+ks], BF[n*2+ks], acc[(MO)+m][(NO)+n], 0, 0, 0); } while (0)

#define STEP(AR, BR, AN, BN, AS, BS, DOSTG, DOEARLY, VM1, VM2, LGM2) do { \
  /* M0: issue bB(4)+aB01(2) [feed M1/M2]; stage A(c+2) s0,s1; MFMA Q00 */ \
  bB[0]=RD16((BR)+4096, arB0);     bB[1]=RD16((BR)+4096, arB1); \
  bB[2]=RD16((BR)+6144, arB0);     bB[3]=RD16((BR)+6144, arB1); \
  aB[0]=RD16((AR)+8192, arA0);     aB[1]=RD16((AR)+8192, arA1); \
  if (DOSTG) { STGA(AS, 0); STGA(AS, 1); } \
  SBAR(); \
  asm volatile("s_waitcnt lgkmcnt(6)" ::: "memory"); __builtin_amdgcn_sched_barrier(0); \
  __builtin_amdgcn_s_setprio(1); MMQ(0, 0, aA, bA); __builtin_amdgcn_s_setprio(0); \
  SBAR(); \
  /* M1: issue aB[2..7] [feed M2]; stage A s2,s3; MFMA Q01; certify A(c+1) */ \
  aB[2]=RD16((AR)+10240, arA0);    aB[3]=RD16((AR)+10240, arA1); \
  aB[4]=RD16((AR)+12288, arA0);    aB[5]=RD16((AR)+12288, arA1); \
  aB[6]=RD16((AR)+14336, arA0);    aB[7]=RD16((AR)+14336, arA1); \
  if (DOSTG) { STGA(AS, 2); STGA(AS, 3); } \
  SBAR(); \
  asm volatile("s_waitcnt lgkmcnt(8)" ::: "memory"); __builtin_amdgcn_sched_barrier(0); \
  __builtin_amdgcn_s_setprio(1); MMQ(0, 2, aA, bB); __builtin_amdgcn_s_setprio(0); \
  asm volatile("s_waitcnt vmcnt(" VM1 ")" ::: "memory"); \
  SBAR(); \
  /* M2: issue aA[0..5] of c+1 [feed next M0]; stage B(c+2) s0,s1; MFMA Q10 */ \
  if (DOEARLY) { \
    aA[0]=RD16((AN), arA0);        aA[1]=RD16((AN), arA1); \
    aA[2]=RD16((AN)+2048, arA0);   aA[3]=RD16((AN)+2048, arA1); \
    aA[4]=RD16((AN)+4096, arA0);   aA[5]=RD16((AN)+4096, arA1); } \
  if (DOSTG) { STGB(BS, 0); STGB(BS, 1); } \
  SBAR(); \
  asm volatile("s_waitcnt lgkmcnt(" LGM2 ")" ::: "memory"); __builtin_amdgcn_sched_barrier(0); \
  __builtin_amdgcn_s_setprio(1); MMQ(4, 0, aB, bA); __builtin_amdgcn_s_setprio(0); \
  asm volatile("s_waitcnt vmcnt(" VM2 ")" ::: "memory"); \
  SBAR(); \
  /* M3: issue aA[6..7]+bA(4) of c+1 [feed next M0]; stage B s2,s3; MFMA Q11 */ \
  if (DOEARLY) { \
    aA[6]=RD16((AN)+6144, arA0);   aA[7]=RD16((AN)+6144, arA1); \
    bA[0]=RD16((BN), arB0);        bA[1]=RD16((BN), arB1); \
    bA[2]=RD16((BN)+2048, arB0);   bA[3]=RD16((BN)+2048, arB1); } \
  if (DOSTG) { STGB(BS, 2); STGB(BS, 3); pa += 64; pb += 64; } \
  SBAR(); __builtin_amdgcn_sched_barrier(0); \
  __builtin_amdgcn_s_setprio(1); MMQ(4, 2, aB, bB); __builtin_amdgcn_s_setprio(0); \
  SBAR(); \
} while (0)

  // ---- prologue: stage A(0),B(0),A(1),B(1) (issue order matters); certify tile0;
  // read tile0's aA(8)+bA(4) (replaces the M2/M3-phase early reads of step -1).
  STGA(AB0, 0); STGA(AB0, 1); STGA(AB0, 2); STGA(AB0, 3);
  STGB(BB0, 0); STGB(BB0, 1); STGB(BB0, 2); STGB(BB0, 3);
  pa += 64; pb += 64;
  STGA(AB1, 0); STGA(AB1, 1); STGA(AB1, 2); STGA(AB1, 3);
  STGB(BB1, 0); STGB(BB1, 1); STGB(BB1, 2); STGB(BB1, 3);
  pa += 64; pb += 64;   // pa/pb now at tile 2
  asm volatile("s_waitcnt vmcnt(8)" ::: "memory");
  SBAR();
  aA[0]=RD16(AB0, arA0);      aA[1]=RD16(AB0, arA1);
  aA[2]=RD16(AB0+2048, arA0); aA[3]=RD16(AB0+2048, arA1);
  aA[4]=RD16(AB0+4096, arA0); aA[5]=RD16(AB0+4096, arA1);
  aA[6]=RD16(AB0+6144, arA0); aA[7]=RD16(AB0+6144, arA1);
  bA[0]=RD16(BB0, arB0);      bA[1]=RD16(BB0, arB1);
  bA[2]=RD16(BB0+2048, arB0); bA[3]=RD16(BB0+2048, arB1);

  const int packs = (NT - 4) / 6;
  for (int it = 0; it < packs; ++it) {
    STEP(AB0, BB0, AB1, BB1, AB2, BB0, 1, 1, "8", "6", "6");
    STEP(AB1, BB1, AB2, BB0, AB0, BB1, 1, 1, "8", "6", "6");
    STEP(AB2, BB0, AB0, BB1, AB1, BB0, 1, 1, "8", "6", "6");
    STEP(AB0, BB1, AB1, BB0, AB2, BB1, 1, 1, "8", "6", "6");
    STEP(AB1, BB0, AB2, BB1, AB0, BB0, 1, 1, "8", "6", "6");
    STEP(AB2, BB1, AB0, BB0, AB1, BB1, 1, 1, "8", "6", "6");
  }
  // tail: c = NT-4 (==0 mod 6), NT-3 (==1), NT-2 (==2, no stage), NT-1 (==3, last)
  STEP(AB0, BB0, AB1, BB1, AB2, BB0, 1, 1, "8", "6", "6");
  STEP(AB1, BB1, AB2, BB0, AB0, BB1, 1, 1, "8", "6", "6");
  STEP(AB2, BB0, AB0, BB1, AB1, BB0, 0, 1, "4", "0", "6");
  STEP(AB0, BB1, AB1, BB0, AB2, BB1, 0, 0, "0", "0", "0");

  // epilogue: D map col = lane&15, row = (lane>>4)*4 + reg
  const int crow = (lane >> 4) * 4;
  const int ccol = lane & 15;
#pragma unroll
  for (int n = 0; n < 4; ++n) {
    int col = n0 + wc * 64 + n * 16 + ccol;
    float bv = bias[col];
#pragma unroll
    for (int m = 0; m < 8; ++m) {
      int row = m0 + wr * 128 + m * 16 + crow;
      float* cp = C + (size_t)row * N + col;
#pragma unroll
      for (int r = 0; r < 4; ++r) cp[(size_t)r * N] = acc[m][n][r] + bv;
    }
  }
#undef RD16
#undef STGA
#undef STGB
#undef MMQ
#undef STEP
#undef AB0
#undef AB1
#undef AB2
#undef BB0
#undef BB1
}

// ---------------- 128x128 m97-structure fallback GEMM ----------------
__global__ __launch_bounds__(256) void gemm_bt_bias(const unsigned short* __restrict__ Xb,
                                                    const unsigned short* __restrict__ Wb,
                                                    const float* __restrict__ bias,
                                                    float* __restrict__ C,
                                                    int M, int N, int K) {
  __shared__ unsigned short sA[128 * 32];
  __shared__ unsigned short sB[128 * 32];
  const int t = threadIdx.x;
  const int wave = t >> 6, lane = t & 63;
  const int NT = N >> 7;
  const int nwg = gridDim.x;
  int bid = blockIdx.x;
  if ((nwg & 7) == 0) bid = (bid & 7) * (nwg >> 3) + (bid >> 3);
  const int tm = bid / NT, tn = bid % NT;
  const int m0 = tm << 7, n0 = tn << 7;
  const int wr = wave >> 1, wc = wave & 1;

  f32x4 acc[4][4];
#pragma unroll
  for (int m = 0; m < 4; ++m)
#pragma unroll
    for (int n = 0; n < 4; ++n) acc[m][n] = (f32x4){0.f, 0.f, 0.f, 0.f};

  const unsigned short* gA0 = Xb + (size_t)(m0 + (t >> 2)) * K + (t & 3) * 8;
  const unsigned short* gA1 = Xb + (size_t)(m0 + 64 + (t >> 2)) * K + (t & 3) * 8;
  const unsigned short* gB0 = Wb + (size_t)(n0 + (t >> 2)) * K + (t & 3) * 8;
  const unsigned short* gB1 = Wb + (size_t)(n0 + 64 + (t >> 2)) * K + (t & 3) * 8;
  unsigned short* lA0 = sA + (size_t)(wave * 64) * 8;
  unsigned short* lA1 = sA + (size_t)(256 + wave * 64) * 8;
  unsigned short* lB0 = sB + (size_t)(wave * 64) * 8;
  unsigned short* lB1 = sB + (size_t)(256 + wave * 64) * 8;

  const int rrow = lane & 15;
  const int rk = (lane >> 4) * 8;

  for (int k0 = 0; k0 < K; k0 += 32) {
    gload_lds16(gA0 + k0, lA0);
    gload_lds16(gA1 + k0, lA1);
    gload_lds16(gB0 + k0, lB0);
    gload_lds16(gB1 + k0, lB1);
    __syncthreads();
    bf16x8 af[4], bfr[4];
#pragma unroll
    for (int m = 0; m < 4; ++m)
      af[m] = *(const bf16x8*)&sA[(size_t)(wr * 64 + m * 16 + rrow) * 32 + rk];
#pragma unroll
    for (int n = 0; n < 4; ++n)
      bfr[n] = *(const bf16x8*)&sB[(size_t)(wc * 64 + n * 16 + rrow) * 32 + rk];
#pragma unroll
    for (int m = 0; m < 4; ++m)
#pragma unroll
      for (int n = 0; n < 4; ++n)
        acc[m][n] = __builtin_amdgcn_mfma_f32_16x16x32_bf16(af[m], bfr[n], acc[m][n], 0, 0, 0);
    __syncthreads();
  }
  const int crow0 = (lane >> 4) * 4;
  const int ccol = lane & 15;
#pragma unroll
  for (int n = 0; n < 4; ++n) {
    int col = n0 + wc * 64 + n * 16 + ccol;
    float bv = bias[col];
#pragma unroll
    for (int m = 0; m < 4; ++m) {
      int row = m0 + wr * 64 + m * 16 + crow0;
      float* cp = C + (size_t)row * N + col;
#pragma unroll
      for (int r = 0; r < 4; ++r) cp[(size_t)r * N] = acc[m][n][r] + bv;
    }
  }
}

// ---------------- fp32 fallback ----------------
__global__ __launch_bounds__(64) void lora_h_kernel(const float* __restrict__ x,
                                                    const float* __restrict__ A,
                                                    float* __restrict__ h,
                                                    float scale, int K, int R) {
  int m = blockIdx.x, lane = threadIdx.x;
  float acc[16];
#pragma unroll
  for (int r = 0; r < 16; ++r) acc[r] = 0.f;
  for (int d = lane; d < K; d += 64) {
    float xv = x[(size_t)m * K + d];
    for (int r = 0; r < R; ++r) acc[r] += xv * A[(size_t)r * K + d];
  }
  for (int off = 32; off; off >>= 1)
    for (int r = 0; r < R; ++r) acc[r] += __shfl_down(acc[r], off);
  if (lane == 0)
    for (int r = 0; r < R; ++r) h[(size_t)m * R + r] = acc[r] * scale;
}

__global__ __launch_bounds__(256) void fgemm_fallback(const float* __restrict__ X,
                                                      const float* __restrict__ W,
                                                      const float* __restrict__ Bm,
                                                      const float* __restrict__ bias,
                                                      const float* __restrict__ h,
                                                      float* __restrict__ C,
                                                      int M, int N, int K, int R) {
  __shared__ float sX[64][20];
  __shared__ float sW[64][20];
  int nt = N >> 6;
  int bx = blockIdx.x % nt, by = blockIdx.x / nt;
  int m0 = by << 6, n0 = bx << 6;
  int t = threadIdx.x;
  int tx = t & 15, ty = t >> 4;
  float acc[4][4] = {};
  int lr = t >> 2, lc = (t & 3) << 2;
  for (int k0 = 0; k0 < K; k0 += 16) {
    *(float4*)&sX[lr][lc] = *(const float4*)&X[(size_t)(m0 + lr) * K + k0 + lc];
    *(float4*)&sW[lr][lc] = *(const float4*)&W[(size_t)(n0 + lr) * K + k0 + lc];
    __syncthreads();
#pragma unroll
    for (int kk = 0; kk < 16; ++kk) {
      float a[4], b[4];
#pragma unroll
      for (int i = 0; i < 4; ++i) a[i] = sX[ty * 4 + i][kk];
#pragma unroll
      for (int j = 0; j < 4; ++j) b[j] = sW[tx * 4 + j][kk];
#pragma unroll
      for (int i = 0; i < 4; ++i)
#pragma unroll
        for (int j = 0; j < 4; ++j) acc[i][j] += a[i] * b[j];
    }
    __syncthreads();
  }
#pragma unroll
  for (int i = 0; i < 4; ++i) {
    int row = m0 + ty * 4 + i;
#pragma unroll
    for (int j = 0; j < 4; ++j) {
      int col = n0 + tx * 4 + j;
      float lo = 0.f;
      for (int r = 0; r < R; ++r) lo += h[(size_t)row * R + r] * Bm[(size_t)col * R + r];
      C[(size_t)row * N + col] = acc[i][j] + bias[col] + lo;
    }
  }
}

extern "C" void kernel_launch(void* const* d_in, const int* in_sizes, int n_in,
                              void* d_out, int out_size, void* d_ws, size_t ws_size,
                              hipStream_t stream) {
  const float* x    = (const float*)d_in[0];
  const float* W    = (const float*)d_in[1];
  const float* A    = (const float*)d_in[2];
  const float* Bm   = (const float*)d_in[3];
  const float* bias = (const float*)d_in[4];
  float* out = (float*)d_out;

  const int N = in_sizes[4];
  const int R = in_sizes[3] / N;
  const int K = in_sizes[2] / R;
  const int M = in_sizes[0] / K;
  const float scale = 16.0f / (float)R;

  const size_t xbytes = (size_t)M * K * 2;
  const size_t wbytes = (size_t)N * K * 2;
  const bool ws_ok = (ws_size >= xbytes + wbytes);
  const int NT = K >> 6;
  const bool fast256 = ws_ok && (M % 256 == 0) && (N % 256 == 0) && (K % 64 == 0) &&
                       (NT % 6 == 4) && (NT >= 10);
  const bool fast128 = ws_ok && (M % 128 == 0) && (N % 128 == 0) && (K % 32 == 0);

  if (fast256 || fast128) {
    unsigned short* xb = (unsigned short*)d_ws;
    unsigned short* wb = (unsigned short*)((char*)d_ws + xbytes);
    int n8 = M * K / 8;
    int t8 = N * K / 8;
    int total = n8 + t8;
    prep_kernel<<<dim3((total + 255) / 256), dim3(256), 0, stream>>>(x, W, A, Bm, xb, wb,
                                                                     scale, K, R, n8, t8);
    if (fast256) {
      int grid = (M / 256) * (N / 256);
      gemm256_bt_bias<<<dim3(grid), dim3(512), 0, stream>>>(xb, wb, bias, out, M, N, K);
    } else {
      int grid = (M / 128) * (N / 128);
      gemm_bt_bias<<<dim3(grid), dim3(256), 0, stream>>>(xb, wb, bias, out, M, N, K);
    }
  } else {
    float* h = (float*)d_ws;
    lora_h_kernel<<<dim3(M), dim3(64), 0, stream>>>(x, A, h, scale, K, R);
    int grid = (M / 64) * (N / 64);
    fgemm_fallback<<<dim3(grid), dim3(256), 0, stream>>>(x, W, Bm, bias, h, out, M, N, K, R);
  }
}

// Round 11
// 329.228 us; speedup vs baseline: 2.5120x; 2.5120x over previous
//
#include <hip/hip_runtime.h>
#include <hip/hip_bf16.h>

typedef short bf16x8 __attribute__((ext_vector_type(8)));
typedef float f32x4 __attribute__((ext_vector_type(4)));
typedef unsigned short ushort8v __attribute__((ext_vector_type(8)));

#define SBAR() asm volatile("s_barrier" ::: "memory")

__device__ __forceinline__ unsigned short f2bf(float f) {
  unsigned u = __builtin_bit_cast(unsigned, f);
  u += 0x7fffu + ((u >> 16) & 1u);   // round-to-nearest-even
  return (unsigned short)(u >> 16);
}

__device__ __forceinline__ void gload_lds16(const unsigned short* g, unsigned short* l) {
  __builtin_amdgcn_global_load_lds((const __attribute__((address_space(1))) void*)g,
                                   (__attribute__((address_space(3))) void*)l, 16, 0, 0);
}

// ---------------- fused prep: xb = bf16(x); wb = bf16(W + scale*B@A) ----------------
__global__ __launch_bounds__(256) void prep_kernel(const float* __restrict__ x,
                                                   const float* __restrict__ W,
                                                   const float* __restrict__ A,
                                                   const float* __restrict__ Bm,
                                                   unsigned short* __restrict__ xb,
                                                   unsigned short* __restrict__ wb,
                                                   float scale, int K, int R, int n8, int t8) {
  int i = blockIdx.x * 256 + threadIdx.x;
  if (i < n8) {
    const float4* p = (const float4*)x + (size_t)i * 2;
    float4 a = p[0], b = p[1];
    ushort8v v;
    v[0] = f2bf(a.x); v[1] = f2bf(a.y); v[2] = f2bf(a.z); v[3] = f2bf(a.w);
    v[4] = f2bf(b.x); v[5] = f2bf(b.y); v[6] = f2bf(b.z); v[7] = f2bf(b.w);
    *((ushort8v*)xb + i) = v;
    return;
  }
  int idx = i - n8;
  if (idx >= t8) return;
  int perRow = K >> 3;
  int n = idx / perRow;
  int d0 = (idx - n * perRow) << 3;
  const float4* wp = (const float4*)(W + (size_t)n * K + d0);
  float4 w0 = wp[0], w1 = wp[1];
  float acc[8] = {w0.x, w0.y, w0.z, w0.w, w1.x, w1.y, w1.z, w1.w};
#pragma unroll 4
  for (int r = 0; r < R; ++r) {
    float c = Bm[(size_t)n * R + r] * scale;
    const float4* ap = (const float4*)(A + (size_t)r * K + d0);
    float4 a0 = ap[0], a1 = ap[1];
    acc[0] += c * a0.x; acc[1] += c * a0.y; acc[2] += c * a0.z; acc[3] += c * a0.w;
    acc[4] += c * a1.x; acc[5] += c * a1.y; acc[6] += c * a1.z; acc[7] += c * a1.w;
  }
  ushort8v v;
#pragma unroll
  for (int j = 0; j < 8; ++j) v[j] = f2bf(acc[j]);
  *((ushort8v*)wb + idx) = v;
}

// -------- 256x256 bf16 GEMM: quarter-phase schedule (m201-model-derived) --------
// BK=64, 8 waves (2Mx4N, wave 128x64), 2 LDS buffers (2x64KB = 128KB).
// Phase = one row-quarter of the wave tile (16 MFMA). B read ONCE per K-tile
// (8 frags in regs across the 4 phases): P1 = 12 ds_reads, P2-P4 = 4 each ->
// LDS drains under MFMA. Stage exactly 2 gload_lds per phase; counted vmcnt(6)
// at phases 4 and 8 ONLY (loads aged 4-7 phases; newest 6 stay in flight).
// A stored quarter-major: site q (8KB) = rows {wr*128 + q*32 .. +31} both wr.
// Buffer (bytes): A q0..q3 at [0,32768); B s0..s3 at [32768,65536); buf1 +65536.
// Swizzle: LDS 16B-chunk c of row lr holds global chunk c ^ (lr&7) (both sides).
__global__ __launch_bounds__(512, 2) void gemm256_bt_bias(const unsigned short* __restrict__ Xb,
                                                          const unsigned short* __restrict__ Wb,
                                                          const float* __restrict__ bias,
                                                          float* __restrict__ C,
                                                          int M, int N, int K) {
  __shared__ __align__(16) char lds[131072];
  const int t = threadIdx.x;
  const int wave = t >> 6, lane = t & 63;
  const int fr = lane & 15, kc = lane >> 4;
  const int wr = wave >> 2, wc = wave & 3;

  const int NTn = N >> 8;
  const int nwg = gridDim.x;
  int bid = blockIdx.x;
  if ((nwg & 7) == 0) bid = (bid & 7) * (nwg >> 3) + (bid >> 3);  // XCD swizzle
  const int tm = bid / NTn, tn = bid % NTn;
  const int m0 = tm << 8, n0 = tn << 8;

  // ---- staging sources (pre-swizzled global chunk) ----
  const int lr = t >> 3;                                  // row-in-site 0..63
  const int gch8 = ((t & 7) ^ (lr & 7)) << 3;             // swizzled chunk, elems
  const unsigned short* pa0 = Xb + (size_t)(m0 + ((lr >> 5) << 7) + (lr & 31)) * K + gch8;
  const unsigned short* pb0 = Wb + (size_t)(n0 + lr) * K + gch8;
  const size_t K32 = (size_t)32 * K, K64v = (size_t)64 * K;
  const int sdst = t * 16;

  // ---- read base pointers (conflict-free swizzle, measured 0 in r8) ----
  const int swz = (fr & 7) << 4;
  const int cb0 = (kc << 4) ^ swz;
  const int cb1 = ((4 + kc) << 4) ^ swz;
  const char* rA00 = (char*)lds + (wr * 32 + fr) * 128 + cb0;   // buf0, ks=0
  const char* rA01 = (char*)lds + (wr * 32 + fr) * 128 + cb1;   // buf0, ks=1
  const char* rA10 = rA00 + 65536;                              // buf1
  const char* rA11 = rA01 + 65536;
  const char* rB00 = (char*)lds + 32768 + wc * 8192 + fr * 128 + cb0;
  const char* rB01 = (char*)lds + 32768 + wc * 8192 + fr * 128 + cb1;
  const char* rB10 = rB00 + 65536;
  const char* rB11 = rB01 + 65536;

  f32x4 acc[8][4];
#pragma unroll
  for (int m = 0; m < 8; ++m)
#pragma unroll
    for (int n = 0; n < 4; ++n) acc[m][n] = (f32x4){0.f, 0.f, 0.f, 0.f};

  bf16x8 aQ[4], bQ[8];

#define STGA(BUF, q, COL) gload_lds16(pa0 + (size_t)(q) * K32 + (COL), \
    (unsigned short*)((char*)lds + (BUF) * 65536 + (q) * 8192 + sdst))
#define STGB(BUF, s, COL) gload_lds16(pb0 + (size_t)(s) * K64v + (COL), \
    (unsigned short*)((char*)lds + (BUF) * 65536 + 32768 + (s) * 8192 + sdst))

#define RDB(R0, R1) do { \
    bQ[0]=*(const bf16x8*)(R0);        bQ[1]=*(const bf16x8*)(R1); \
    bQ[2]=*(const bf16x8*)((R0)+2048); bQ[3]=*(const bf16x8*)((R1)+2048); \
    bQ[4]=*(const bf16x8*)((R0)+4096); bQ[5]=*(const bf16x8*)((R1)+4096); \
    bQ[6]=*(const bf16x8*)((R0)+6144); bQ[7]=*(const bf16x8*)((R1)+6144); } while (0)
#define RDA(R0, R1, q) do { \
    aQ[0]=*(const bf16x8*)((R0)+(q)*8192);      aQ[1]=*(const bf16x8*)((R1)+(q)*8192); \
    aQ[2]=*(const bf16x8*)((R0)+(q)*8192+2048); aQ[3]=*(const bf16x8*)((R1)+(q)*8192+2048); } while (0)

#define MMQ(q) do { __builtin_amdgcn_s_setprio(1); \
    _Pragma("unroll") for (int mq = 0; mq < 2; ++mq) \
    _Pragma("unroll") for (int n = 0; n < 4; ++n) \
    _Pragma("unroll") for (int ks = 0; ks < 2; ++ks) \
      acc[(q)*2+mq][n] = __builtin_amdgcn_mfma_f32_16x16x32_bf16( \
          aQ[mq*2+ks], bQ[n*2+ks], acc[(q)*2+mq][n], 0, 0, 0); \
    __builtin_amdgcn_s_setprio(0); } while (0)

  // phase: reads -> stage -> [vmcnt] -> SBAR -> lgkm(0) -> 16 MFMA -> SBAR
#define PH(RA0, RA1, q, STGS, WAITS) do { \
    RDA(RA0, RA1, q); \
    STGS WAITS \
    SBAR(); \
    asm volatile("s_waitcnt lgkmcnt(0)" ::: "memory"); \
    __builtin_amdgcn_sched_barrier(0); \
    MMQ(q); \
    SBAR(); } while (0)
#define PH_B(RA0, RA1, RB0, RB1, STGS, WAITS) do { \
    RDB(RB0, RB1); RDA(RA0, RA1, 0); \
    STGS WAITS \
    SBAR(); \
    asm volatile("s_waitcnt lgkmcnt(0)" ::: "memory"); \
    __builtin_amdgcn_sched_barrier(0); \
    MMQ(0); \
    SBAR(); } while (0)

  // iter = 2 K-tiles (buf0 then buf1). Stage ledger (steady):
  // P1: Aq2,Aq3(c+1)  P2: Bs0,Bs1(c+2)  P3: Bs2,Bs3(c+2)  P4: Aq0,Aq1(c+2)
  // P5: Aq2,Aq3(c+2)  P6: Bs0,Bs1(c+3)  P7: Bs2,Bs3(c+3)  P8: Aq0,Aq1(c+3)
  // vmcnt(6)@P4 and @P8 certify everything older than the newest 6 loads.
#define ITER(DOSTG, VM4, VM8) do { \
    PH_B(rA00, rA01, rB00, rB01, { STGA(1, 2, col + 64); STGA(1, 3, col + 64); }, ;); \
    PH(rA00, rA01, 1, { if (DOSTG) { STGB(0, 0, col + 128); STGB(0, 1, col + 128); } }, ;); \
    PH(rA00, rA01, 2, { if (DOSTG) { STGB(0, 2, col + 128); STGB(0, 3, col + 128); } }, ;); \
    PH(rA00, rA01, 3, { if (DOSTG) { STGA(0, 0, col + 128); STGA(0, 1, col + 128); } }, \
       asm volatile("s_waitcnt vmcnt(" VM4 ")" ::: "memory");); \
    PH_B(rA10, rA11, rB10, rB11, { if (DOSTG) { STGA(0, 2, col + 128); STGA(0, 3, col + 128); } }, ;); \
    PH(rA10, rA11, 1, { if (DOSTG) { STGB(1, 0, col + 192); STGB(1, 1, col + 192); } }, ;); \
    PH(rA10, rA11, 2, { if (DOSTG) { STGB(1, 2, col + 192); STGB(1, 3, col + 192); } }, ;); \
    PH(rA10, rA11, 3, { if (DOSTG) { STGA(1, 0, col + 192); STGA(1, 1, col + 192); } }, \
       asm volatile("s_waitcnt vmcnt(" VM8 ")" ::: "memory");); \
    col += 128; } while (0)

  // prologue: tile0 full (8), B(1) (4), Aq0,Aq1(1) (2) = 14 loads;
  // vmcnt(6) certifies tile0, leaves exactly the steady-state 6 in flight.
  size_t col = 0;
  STGB(0, 0, 0); STGB(0, 1, 0); STGB(0, 2, 0); STGB(0, 3, 0);
  STGA(0, 0, 0); STGA(0, 1, 0); STGA(0, 2, 0); STGA(0, 3, 0);
  STGB(1, 0, 64); STGB(1, 1, 64); STGB(1, 2, 64); STGB(1, 3, 64);
  STGA(1, 0, 64); STGA(1, 1, 64);
  asm volatile("s_waitcnt vmcnt(6)" ::: "memory");
  SBAR();

  const int NITER = K >> 7;   // launcher guarantees K%128==0, K>=256
  for (int it = 0; it < NITER - 1; ++it) ITER(1, "6", "6");
  ITER(0, "0", "0");          // last iter: P1 still stages Aq2,Aq3(NT-1); drain

  // epilogue: D map col = lane&15, row = (lane>>4)*4 + reg
  const int crow = (lane >> 4) * 4;
  const int ccol = lane & 15;
#pragma unroll
  for (int n = 0; n < 4; ++n) {
    int ccol2 = n0 + wc * 64 + n * 16 + ccol;
    float bv = bias[ccol2];
#pragma unroll
    for (int m = 0; m < 8; ++m) {
      int row = m0 + wr * 128 + m * 16 + crow;
      float* cp = C + (size_t)row * N + ccol2;
#pragma unroll
      for (int r = 0; r < 4; ++r) cp[(size_t)r * N] = acc[m][n][r] + bv;
    }
  }
#undef STGA
#undef STGB
#undef RDB
#undef RDA
#undef MMQ
#undef PH
#undef PH_B
#undef ITER
}

// ---------------- 128x128 m97-structure fallback GEMM ----------------
__global__ __launch_bounds__(256) void gemm_bt_bias(const unsigned short* __restrict__ Xb,
                                                    const unsigned short* __restrict__ Wb,
                                                    const float* __restrict__ bias,
                                                    float* __restrict__ C,
                                                    int M, int N, int K) {
  __shared__ unsigned short sA[128 * 32];
  __shared__ unsigned short sB[128 * 32];
  const int t = threadIdx.x;
  const int wave = t >> 6, lane = t & 63;
  const int NT = N >> 7;
  const int nwg = gridDim.x;
  int bid = blockIdx.x;
  if ((nwg & 7) == 0) bid = (bid & 7) * (nwg >> 3) + (bid >> 3);
  const int tm = bid / NT, tn = bid % NT;
  const int m0 = tm << 7, n0 = tn << 7;
  const int wr = wave >> 1, wc = wave & 1;

  f32x4 acc[4][4];
#pragma unroll
  for (int m = 0; m < 4; ++m)
#pragma unroll
    for (int n = 0; n < 4; ++n) acc[m][n] = (f32x4){0.f, 0.f, 0.f, 0.f};

  const unsigned short* gA0 = Xb + (size_t)(m0 + (t >> 2)) * K + (t & 3) * 8;
  const unsigned short* gA1 = Xb + (size_t)(m0 + 64 + (t >> 2)) * K + (t & 3) * 8;
  const unsigned short* gB0 = Wb + (size_t)(n0 + (t >> 2)) * K + (t & 3) * 8;
  const unsigned short* gB1 = Wb + (size_t)(n0 + 64 + (t >> 2)) * K + (t & 3) * 8;
  unsigned short* lA0 = sA + (size_t)(wave * 64) * 8;
  unsigned short* lA1 = sA + (size_t)(256 + wave * 64) * 8;
  unsigned short* lB0 = sB + (size_t)(wave * 64) * 8;
  unsigned short* lB1 = sB + (size_t)(256 + wave * 64) * 8;

  const int rrow = lane & 15;
  const int rk = (lane >> 4) * 8;

  for (int k0 = 0; k0 < K; k0 += 32) {
    gload_lds16(gA0 + k0, lA0);
    gload_lds16(gA1 + k0, lA1);
    gload_lds16(gB0 + k0, lB0);
    gload_lds16(gB1 + k0, lB1);
    __syncthreads();
    bf16x8 af[4], bfr[4];
#pragma unroll
    for (int m = 0; m < 4; ++m)
      af[m] = *(const bf16x8*)&sA[(size_t)(wr * 64 + m * 16 + rrow) * 32 + rk];
#pragma unroll
    for (int n = 0; n < 4; ++n)
      bfr[n] = *(const bf16x8*)&sB[(size_t)(wc * 64 + n * 16 + rrow) * 32 + rk];
#pragma unroll
    for (int m = 0; m < 4; ++m)
#pragma unroll
      for (int n = 0; n < 4; ++n)
        acc[m][n] = __builtin_amdgcn_mfma_f32_16x16x32_bf16(af[m], bfr[n], acc[m][n], 0, 0, 0);
    __syncthreads();
  }
  const int crow0 = (lane >> 4) * 4;
  const int ccol = lane & 15;
#pragma unroll
  for (int n = 0; n < 4; ++n) {
    int col = n0 + wc * 64 + n * 16 + ccol;
    float bv = bias[col];
#pragma unroll
    for (int m = 0; m < 4; ++m) {
      int row = m0 + wr * 64 + m * 16 + crow0;
      float* cp = C + (size_t)row * N + col;
#pragma unroll
      for (int r = 0; r < 4; ++r) cp[(size_t)r * N] = acc[m][n][r] + bv;
    }
  }
}

// ---------------- fp32 fallback ----------------
__global__ __launch_bounds__(64) void lora_h_kernel(const float* __restrict__ x,
                                                    const float* __restrict__ A,
                                                    float* __restrict__ h,
                                                    float scale, int K, int R) {
  int m = blockIdx.x, lane = threadIdx.x;
  float acc[16];
#pragma unroll
  for (int r = 0; r < 16; ++r) acc[r] = 0.f;
  for (int d = lane; d < K; d += 64) {
    float xv = x[(size_t)m * K + d];
    for (int r = 0; r < R; ++r) acc[r] += xv * A[(size_t)r * K + d];
  }
  for (int off = 32; off; off >>= 1)
    for (int r = 0; r < R; ++r) acc[r] += __shfl_down(acc[r], off);
  if (lane == 0)
    for (int r = 0; r < R; ++r) h[(size_t)m * R + r] = acc[r] * scale;
}

__global__ __launch_bounds__(256) void fgemm_fallback(const float* __restrict__ X,
                                                      const float* __restrict__ W,
                                                      const float* __restrict__ Bm,
                                                      const float* __restrict__ bias,
                                                      const float* __restrict__ h,
                                                      float* __restrict__ C,
                                                      int M, int N, int K, int R) {
  __shared__ float sX[64][20];
  __shared__ float sW[64][20];
  int nt = N >> 6;
  int bx = blockIdx.x % nt, by = blockIdx.x / nt;
  int m0 = by << 6, n0 = bx << 6;
  int t = threadIdx.x;
  int tx = t & 15, ty = t >> 4;
  float acc[4][4] = {};
  int lrr = t >> 2, lc = (t & 3) << 2;
  for (int k0 = 0; k0 < K; k0 += 16) {
    *(float4*)&sX[lrr][lc] = *(const float4*)&X[(size_t)(m0 + lrr) * K + k0 + lc];
    *(float4*)&sW[lrr][lc] = *(const float4*)&W[(size_t)(n0 + lrr) * K + k0 + lc];
    __syncthreads();
#pragma unroll
    for (int kk = 0; kk < 16; ++kk) {
      float a[4], b[4];
#pragma unroll
      for (int i = 0; i < 4; ++i) a[i] = sX[ty * 4 + i][kk];
#pragma unroll
      for (int j = 0; j < 4; ++j) b[j] = sW[tx * 4 + j][kk];
#pragma unroll
      for (int i = 0; i < 4; ++i)
#pragma unroll
        for (int j = 0; j < 4; ++j) acc[i][j] += a[i] * b[j];
    }
    __syncthreads();
  }
#pragma unroll
  for (int i = 0; i < 4; ++i) {
    int row = m0 + ty * 4 + i;
#pragma unroll
    for (int j = 0; j < 4; ++j) {
      int col = n0 + tx * 4 + j;
      float lo = 0.f;
      for (int r = 0; r < R; ++r) lo += h[(size_t)row * R + r] * Bm[(size_t)col * R + r];
      C[(size_t)row * N + col] = acc[i][j] + bias[col] + lo;
    }
  }
}

extern "C" void kernel_launch(void* const* d_in, const int* in_sizes, int n_in,
                              void* d_out, int out_size, void* d_ws, size_t ws_size,
                              hipStream_t stream) {
  const float* x    = (const float*)d_in[0];
  const float* W    = (const float*)d_in[1];
  const float* A    = (const float*)d_in[2];
  const float* Bm   = (const float*)d_in[3];
  const float* bias = (const float*)d_in[4];
  float* out = (float*)d_out;

  const int N = in_sizes[4];
  const int R = in_sizes[3] / N;
  const int K = in_sizes[2] / R;
  const int M = in_sizes[0] / K;
  const float scale = 16.0f / (float)R;

  const size_t xbytes = (size_t)M * K * 2;
  const size_t wbytes = (size_t)N * K * 2;
  const bool ws_ok = (ws_size >= xbytes + wbytes);
  const bool fast256 = ws_ok && (M % 256 == 0) && (N % 256 == 0) && (K % 128 == 0) && (K >= 256);
  const bool fast128 = ws_ok && (M % 128 == 0) && (N % 128 == 0) && (K % 32 == 0);

  if (fast256 || fast128) {
    unsigned short* xb = (unsigned short*)d_ws;
    unsigned short* wb = (unsigned short*)((char*)d_ws + xbytes);
    int n8 = M * K / 8;
    int t8 = N * K / 8;
    int total = n8 + t8;
    prep_kernel<<<dim3((total + 255) / 256), dim3(256), 0, stream>>>(x, W, A, Bm, xb, wb,
                                                                     scale, K, R, n8, t8);
    if (fast256) {
      int grid = (M / 256) * (N / 256);
      gemm256_bt_bias<<<dim3(grid), dim3(512), 0, stream>>>(xb, wb, bias, out, M, N, K);
    } else {
      int grid = (M / 128) * (N / 128);
      gemm_bt_bias<<<dim3(grid), dim3(256), 0, stream>>>(xb, wb, bias, out, M, N, K);
    }
  } else {
    float* h = (float*)d_ws;
    lora_h_kernel<<<dim3(M), dim3(64), 0, stream>>>(x, A, h, scale, K, R);
    int grid = (M / 64) * (N / 64);
    fgemm_fallback<<<dim3(grid), dim3(256), 0, stream>>>(x, W, Bm, bias, h, out, M, N, K, R);
  }
}